// Round 5
// baseline (724.832 us; speedup 1.0000x reference)
//
#include <hip/hip_runtime.h>

// Problem constants (fixed by setup_inputs): im0 [B,C,H,W] fp32,
// flow [B,H,W,2] fp32, out [B,C,H,W] fp32.
constexpr int B_ = 4;
constexpr int C_ = 3;
constexpr int H_ = 1024;
constexpr int W_ = 1920;
constexpr int HW_ = H_ * W_;

// Gather formulation (see R1-R3 journal): each block OWNS a TW x TH output
// tile, all 3 channels accumulated in LDS via ds_add_f32; scans the
// (TW+2R)x(TH+2R) source halo; splat corners with |disp|<=R landing in the
// tile are accumulated locally; output written with plain coalesced float4
// stores (every output pixel owned by exactly one block -> no memset, no
// global atomics in the main path). Far corners (|disp|>R) partition to a
// second pass.
//
// R4b changes (R4 resubmit after infra failure, ballot-append simplified):
//  (a) far pixels are detected inline during the core scan (superset filter
//      |f|>15, matching the old fw_far prefilter exactly) and their indices
//      appended to a d_ws record list (plain per-lane atomicAdd; compiler
//      coalesces the counter bump per wave); fw_far_rec then processes
//      ~42k records instead of rescanning all 7.9M pixels (~175 us).
//  (b) LDS channel planes padded 4096->4100 words so the 3 channel-atomics
//      per corner hit banks b, b+4, b+8 instead of the same bank.
constexpr int TW = 64;
constexpr int TH = 64;
constexpr int R  = 16;
constexpr int EW = TW + 2 * R;      // 96
constexpr int EH = TH + 2 * R;      // 96
constexpr int TCELLS = TW * TH;     // 4096
constexpr int PLANE  = TCELLS + 4;  // +4 words: de-alias banks, keep 16B align
constexpr int NTHR = 512;
constexpr int QPR = EW / 4;         // 24 quads per halo row
constexpr int NQ  = QPR * EH;       // 2304 quads

static_assert(W_ % TW == 0 && H_ % TH == 0, "exact tiling assumed");
static_assert(W_ % 4 == 0 && EW % 4 == 0, "quad alignment assumed");

__global__ __launch_bounds__(NTHR, 6) void fw_gather(
    const float* __restrict__ im0,
    const float2* __restrict__ flow,
    const int* __restrict__ mode_p,
    float* __restrict__ out,
    int* __restrict__ far_cnt,
    int* __restrict__ far_rec,
    const int far_cap) {
    __shared__ float tile[C_ * PLANE];

    const int tx0 = blockIdx.x * TW;
    const int ty0 = blockIdx.y * TH;
    const int b   = blockIdx.z;
    const int mode = *mode_p;                  // wave-uniform

    for (int i = threadIdx.x; i < C_ * PLANE; i += NTHR) tile[i] = 0.0f;
    __syncthreads();

    const float*  im0b  = im0  + (size_t)b * C_ * HW_;
    const float2* flowb = flow + (size_t)b * HW_;

    for (int q = threadIdx.x; q < NQ; q += NTHR) {
        const int qy = q / QPR;                // magic-mul div
        const int qxl = (q - qy * QPR) * 4;    // local x of quad start
        const int gy = ty0 - R + qy;
        const int gx = tx0 - R + qxl;
        if ((unsigned)gy >= (unsigned)H_) continue;
        if ((unsigned)gx >= (unsigned)W_) continue;
        // core iff this quad lies in the block's owned TWxTH region
        const bool is_core = ((unsigned)(qy - R) < (unsigned)TH) &&
                             ((unsigned)(qxl - R) < (unsigned)TW);

        const int src = gy * W_ + gx;          // multiple of 4
        const float4 f01 = reinterpret_cast<const float4*>(flowb)[src >> 1];
        const float4 f23 = reinterpret_cast<const float4*>(flowb)[(src >> 1) + 1];
        const float4 sA  = reinterpret_cast<const float4*>(im0b)[src >> 2];
        const float4 sB  = reinterpret_cast<const float4*>(im0b + HW_)[src >> 2];
        const float4 sC  = reinterpret_cast<const float4*>(im0b + 2 * HW_)[src >> 2];

        const float fx[4] = { f01.x, f01.z, f23.x, f23.z };
        const float fy[4] = { f01.y, f01.w, f23.y, f23.w };
        const float s0[4] = { sA.x, sA.y, sA.z, sA.w };
        const float s1[4] = { sB.x, sB.y, sB.z, sB.w };
        const float s2[4] = { sC.x, sC.y, sC.z, sC.w };

        // Far-pixel detection (core pixels only; each pixel is core of
        // exactly one block -> no duplicate records). Superset filter
        // identical to the old fw_far prefilter: survives iff
        // !(|fx|<15 && |fy|<15). fw_far_rec applies the exact condition.
        if (far_cap > 0 && is_core) {
            const float lim = (float)(R - 1);
#pragma unroll
            for (int i = 0; i < 4; ++i) {
                if (!(fabsf(fx[i]) < lim && fabsf(fy[i]) < lim)) {
                    const int slot = atomicAdd(far_cnt, 1);
                    if (slot < far_cap)
                        far_rec[slot] = b * HW_ + gy * W_ + (gx + i);
                }
            }
        }

        if (mode == 1) {                       // nearest
#pragma unroll
            for (int i = 0; i < 4; ++i) {
                const int gxi = gx + i;
                const int cx = (int)rintf((float)gxi + fx[i]);
                const int cy = (int)rintf((float)gy  + fy[i]);
                const int ltx = cx - tx0, lty = cy - ty0;
                const int dx = cx - gxi, dy = cy - gy;
                if ((unsigned)ltx < (unsigned)TW && (unsigned)lty < (unsigned)TH &&
                    dx >= -R && dx <= R && dy >= -R && dy <= R) {
                    const int idx = lty * TW + ltx;
                    unsafeAtomicAdd(&tile[0 * PLANE + idx], s0[i]);
                    unsafeAtomicAdd(&tile[1 * PLANE + idx], s1[i]);
                    unsafeAtomicAdd(&tile[2 * PLANE + idx], s2[i]);
                }
            }
        } else {                               // bilinear, 4 corners
#pragma unroll
            for (int i = 0; i < 4; ++i) {
                const int gxi = gx + i;
                const float px = (float)gxi + fx[i];
                const float py = (float)gy  + fy[i];
                const float xf = floorf(px), yf = floorf(py);
                const int x0 = (int)xf, y0 = (int)yf;
                const float wx1 = px - xf, wy1 = py - yf;
                const float wx0 = 1.0f - wx1, wy0 = 1.0f - wy1;

                const int lx0 = x0 - tx0, ly0 = y0 - ty0;
                const int dx0 = x0 - gxi, dy0 = y0 - gy;
                const bool vx0 = ((unsigned)lx0 < (unsigned)TW) &&
                                 (dx0 >= -R) && (dx0 <= R);
                const bool vx1 = ((unsigned)(lx0 + 1) < (unsigned)TW) &&
                                 (dx0 + 1 >= -R) && (dx0 + 1 <= R);
                const bool vy0 = ((unsigned)ly0 < (unsigned)TH) &&
                                 (dy0 >= -R) && (dy0 <= R);
                const bool vy1 = ((unsigned)(ly0 + 1) < (unsigned)TH) &&
                                 (dy0 + 1 >= -R) && (dy0 + 1 <= R);
                if (!((vx0 || vx1) && (vy0 || vy1))) continue;

                const int idx00 = ly0 * TW + lx0;
                if (vy0) {
                    if (vx0) {
                        const float w = wx0 * wy0;
                        unsafeAtomicAdd(&tile[0 * PLANE + idx00], s0[i] * w);
                        unsafeAtomicAdd(&tile[1 * PLANE + idx00], s1[i] * w);
                        unsafeAtomicAdd(&tile[2 * PLANE + idx00], s2[i] * w);
                    }
                    if (vx1) {
                        const float w = wx1 * wy0;
                        unsafeAtomicAdd(&tile[0 * PLANE + idx00 + 1], s0[i] * w);
                        unsafeAtomicAdd(&tile[1 * PLANE + idx00 + 1], s1[i] * w);
                        unsafeAtomicAdd(&tile[2 * PLANE + idx00 + 1], s2[i] * w);
                    }
                }
                if (vy1) {
                    if (vx0) {
                        const float w = wx0 * wy1;
                        unsafeAtomicAdd(&tile[0 * PLANE + idx00 + TW], s0[i] * w);
                        unsafeAtomicAdd(&tile[1 * PLANE + idx00 + TW], s1[i] * w);
                        unsafeAtomicAdd(&tile[2 * PLANE + idx00 + TW], s2[i] * w);
                    }
                    if (vx1) {
                        const float w = wx1 * wy1;
                        unsafeAtomicAdd(&tile[0 * PLANE + idx00 + TW + 1], s0[i] * w);
                        unsafeAtomicAdd(&tile[1 * PLANE + idx00 + TW + 1], s1[i] * w);
                        unsafeAtomicAdd(&tile[2 * PLANE + idx00 + TW + 1], s2[i] * w);
                    }
                }
            }
        }
    }
    __syncthreads();

    // Dense, coalesced, NON-atomic float4 stores.
    for (int i = threadIdx.x; i < C_ * (TCELLS / 4); i += NTHR) {
        const int c    = i >> 10;              // TCELLS/4 == 1024
        const int j    = i & 1023;
        const int row  = j >> 4;               // 16 float4 per 64-wide row
        const int col4 = j & 15;
        const float4 v =
            *reinterpret_cast<const float4*>(&tile[c * PLANE + (j << 2)]);
        float* dst = out + ((size_t)(b * C_ + c)) * HW_ +
                     (size_t)(ty0 + row) * W_ + tx0 + col4 * 4;
        *reinterpret_cast<float4*>(dst) = v;
    }
}

// Shared far-corner body (exact condition; complement of the gather path).
__device__ __forceinline__ void far_pixel_body(
    const float* __restrict__ im0, float* __restrict__ out,
    int b, int gx, int gy, float fxv, float fyv, int mode) {
    const float px = (float)gx + fxv;
    const float py = (float)gy + fyv;
    const float* im0b = im0 + (size_t)b * C_ * HW_;
    float*       outb = out + (size_t)b * C_ * HW_;
    const int src = gy * W_ + gx;

    if (mode == 1) {
        const int cx = (int)rintf(px);
        const int cy = (int)rintf(py);
        const int dx = cx - gx, dy = cy - gy;
        const bool in = (unsigned)cx < (unsigned)W_ &&
                        (unsigned)cy < (unsigned)H_;
        if (in && (dx < -R || dx > R || dy < -R || dy > R)) {
            const int dsti = cy * W_ + cx;
            unsafeAtomicAdd(outb + dsti,            im0b[src]);
            unsafeAtomicAdd(outb + HW_ + dsti,      im0b[src + HW_]);
            unsafeAtomicAdd(outb + 2 * HW_ + dsti,  im0b[src + 2 * HW_]);
        }
    } else {
        const float xf = floorf(px), yf = floorf(py);
        const int x0 = (int)xf, y0 = (int)yf;
        const float wx1 = px - xf, wy1 = py - yf;
        const float wx0 = 1.0f - wx1, wy0 = 1.0f - wy1;

        const int   cxs[4] = { x0, x0 + 1, x0,     x0 + 1 };
        const int   cys[4] = { y0, y0,     y0 + 1, y0 + 1 };
        const float cws[4] = { wx0 * wy0, wx1 * wy0, wx0 * wy1, wx1 * wy1 };

        bool m[4];
        bool any = false;
#pragma unroll
        for (int k = 0; k < 4; ++k) {
            const int dx = cxs[k] - gx, dy = cys[k] - gy;
            const bool in = (unsigned)cxs[k] < (unsigned)W_ &&
                            (unsigned)cys[k] < (unsigned)H_;
            m[k] = in && (dx < -R || dx > R || dy < -R || dy > R);
            any = any || m[k];
        }
        if (!any) return;

        const float s0 = im0b[src];
        const float s1 = im0b[src + HW_];
        const float s2 = im0b[src + 2 * HW_];
#pragma unroll
        for (int k = 0; k < 4; ++k) {
            if (m[k]) {
                const int dsti = cys[k] * W_ + cxs[k];
                const float w = cws[k];
                unsafeAtomicAdd(outb + dsti,           s0 * w);
                unsafeAtomicAdd(outb + HW_ + dsti,     s1 * w);
                unsafeAtomicAdd(outb + 2 * HW_ + dsti, s2 * w);
            }
        }
    }
}

// Record-driven far pass: ~42k records instead of a 7.9M-pixel rescan.
__global__ __launch_bounds__(256) void fw_far_rec(
    const float* __restrict__ im0,
    const float2* __restrict__ flow,
    const int* __restrict__ mode_p,
    float* __restrict__ out,
    const int* __restrict__ far_cnt,
    const int* __restrict__ far_rec,
    const int far_cap) {
    const int mode = *mode_p;
    int n = *far_cnt;
    if (n > far_cap) n = far_cap;
    for (int i = blockIdx.x * 256 + threadIdx.x; i < n; i += gridDim.x * 256) {
        const int pix = far_rec[i];
        const int b   = pix / HW_;
        const int rem = pix - b * HW_;
        const int gy  = rem / W_;
        const int gx  = rem - gy * W_;
        const float2 f = flow[pix];
        far_pixel_body(im0, out, b, gx, gy, f.x, f.y, mode);
    }
}

// Fallback full-scan far pass (used only if d_ws is too small).
__global__ __launch_bounds__(256) void fw_far_scan(
    const float* __restrict__ im0,
    const float2* __restrict__ flow,
    const int* __restrict__ mode_p,
    float* __restrict__ out) {
    const int idx = blockIdx.x * 256 + threadIdx.x;
    if (idx >= B_ * HW_) return;
    const float2 f = flow[idx];
    const float lim = (float)(R - 1);
    if (fabsf(f.x) < lim && fabsf(f.y) < lim) return;
    const int mode = *mode_p;
    const int b   = idx / HW_;
    const int rem = idx - b * HW_;
    const int gy  = rem / W_;
    const int gx  = rem - gy * W_;
    far_pixel_body(im0, out, b, gx, gy, f.x, f.y, mode);
}

extern "C" void kernel_launch(void* const* d_in, const int* in_sizes, int n_in,
                              void* d_out, int out_size, void* d_ws, size_t ws_size,
                              hipStream_t stream) {
    const float*  im0  = (const float*)d_in[0];
    const float2* flow = (const float2*)d_in[1];
    // d_in[2] = flowback (unused by the forward splat)
    const int*    mode = (const int*)d_in[3];
    float* out = (float*)d_out;

    dim3 grid(W_ / TW, H_ / TH, B_);

    int* cnt = (int*)d_ws;
    int* rec = cnt + 16;
    // Need headroom for the record list; bench inputs produce ~42k records.
    const long long cap_ll = (long long)(ws_size / 4) - 16;
    const int cap = (ws_size >= (1u << 16))
                        ? (int)(cap_ll > 0x7fffffff ? 0x7fffffff : cap_ll)
                        : 0;

    if (cap > 0) {
        (void)hipMemsetAsync(d_ws, 0, sizeof(int), stream);
        fw_gather<<<grid, dim3(NTHR), 0, stream>>>(im0, flow, mode, out,
                                                   cnt, rec, cap);
        fw_far_rec<<<dim3(256), dim3(256), 0, stream>>>(im0, flow, mode, out,
                                                        cnt, rec, cap);
    } else {
        fw_gather<<<grid, dim3(NTHR), 0, stream>>>(im0, flow, mode, out,
                                                   nullptr, nullptr, 0);
        constexpr int total = B_ * HW_;
        fw_far_scan<<<dim3((total + 255) / 256), dim3(256), 0, stream>>>(
            im0, flow, mode, out);
    }
}

// Round 6
// 698.104 us; speedup vs baseline: 1.0383x; 1.0383x over previous
//
#include <hip/hip_runtime.h>

// Problem constants (fixed by setup_inputs): im0 [B,C,H,W] fp32,
// flow [B,H,W,2] fp32, out [B,C,H,W] fp32.
constexpr int B_ = 4;
constexpr int C_ = 3;
constexpr int H_ = 1024;
constexpr int W_ = 1920;
constexpr int HW_ = H_ * W_;

// Gather formulation (journal R1-R5): each block OWNS a TW x TH output
// tile, 3 channels accumulated in LDS via ds_add_f32; scans the
// (TW+2R)x(TH+2R) source halo; splat corners with |disp|<=R landing in the
// tile are accumulated locally; output written with plain coalesced float4
// stores. Far corners (|disp|>R) go to fw_far (flat full scan -- measured
// cheap in R3; the R4/R5 record compaction was overhead, reverted).
//
// R6: LDS tile row stride 64 -> 68. With stride 64, bank = ltx mod 32:
// within one ds_add instruction lanes sit at ltx = 4*(lane%24)+i+dx
// (dx~N(0,5)), clustering on 8 bank classes -> structural ~8-way conflict
// on all 1.47M atomic wave-instrs (~2.9x serialization, m136) -- the
// invariant ~520us. Stride 68 -> bank = (4*lty+ltx) mod 32: random dy
// scatters lanes across classes (expected ~1.5x residual). Rows stay
// 16B-aligned (68*4=272), so the float4 flush is unchanged. Channel plane
// = 68*64+4 = 4356 words -> +4 bank shift per channel, 52272 B LDS,
// still 3 blocks/CU.
constexpr int TW = 64;
constexpr int TH = 64;
constexpr int R  = 16;
constexpr int EW = TW + 2 * R;      // 96
constexpr int EH = TH + 2 * R;      // 96
constexpr int RS = 68;              // tile row stride (words): bank swizzle
constexpr int PLANE = RS * TH + 4;  // 4356 words; +4 de-aliases channels
constexpr int NTHR = 512;
constexpr int QPR = EW / 4;         // 24 quads per halo row
constexpr int NQ  = QPR * EH;       // 2304 quads

static_assert(W_ % TW == 0 && H_ % TH == 0, "exact tiling assumed");
static_assert(W_ % 4 == 0 && EW % 4 == 0, "quad alignment assumed");
static_assert((RS * 4) % 16 == 0 && (PLANE * 4) % 16 == 0, "16B-aligned rows");
static_assert(3 * PLANE * 4 <= 54613, "3 blocks/CU LDS budget");

__global__ __launch_bounds__(NTHR, 6) void fw_gather(
    const float* __restrict__ im0,
    const float2* __restrict__ flow,
    const int* __restrict__ mode_p,
    float* __restrict__ out) {
    __shared__ float tile[C_ * PLANE];

    const int tx0 = blockIdx.x * TW;
    const int ty0 = blockIdx.y * TH;
    const int b   = blockIdx.z;
    const int mode = *mode_p;                  // wave-uniform

    for (int i = threadIdx.x; i < C_ * PLANE; i += NTHR) tile[i] = 0.0f;
    __syncthreads();

    const float*  im0b  = im0  + (size_t)b * C_ * HW_;
    const float2* flowb = flow + (size_t)b * HW_;

    for (int q = threadIdx.x; q < NQ; q += NTHR) {
        const int qy = q / QPR;                // magic-mul div
        const int qxl = (q - qy * QPR) * 4;    // local x of quad start
        const int gy = ty0 - R + qy;
        const int gx = tx0 - R + qxl;
        if ((unsigned)gy >= (unsigned)H_) continue;
        if ((unsigned)gx >= (unsigned)W_) continue;

        const int src = gy * W_ + gx;          // multiple of 4
        const float4 f01 = reinterpret_cast<const float4*>(flowb)[src >> 1];
        const float4 f23 = reinterpret_cast<const float4*>(flowb)[(src >> 1) + 1];
        const float4 sA  = reinterpret_cast<const float4*>(im0b)[src >> 2];
        const float4 sB  = reinterpret_cast<const float4*>(im0b + HW_)[src >> 2];
        const float4 sC  = reinterpret_cast<const float4*>(im0b + 2 * HW_)[src >> 2];

        const float fx[4] = { f01.x, f01.z, f23.x, f23.z };
        const float fy[4] = { f01.y, f01.w, f23.y, f23.w };
        const float s0[4] = { sA.x, sA.y, sA.z, sA.w };
        const float s1[4] = { sB.x, sB.y, sB.z, sB.w };
        const float s2[4] = { sC.x, sC.y, sC.z, sC.w };

        if (mode == 1) {                       // nearest
#pragma unroll
            for (int i = 0; i < 4; ++i) {
                const int gxi = gx + i;
                const int cx = (int)rintf((float)gxi + fx[i]);
                const int cy = (int)rintf((float)gy  + fy[i]);
                const int ltx = cx - tx0, lty = cy - ty0;
                const int dx = cx - gxi, dy = cy - gy;
                if ((unsigned)ltx < (unsigned)TW && (unsigned)lty < (unsigned)TH &&
                    dx >= -R && dx <= R && dy >= -R && dy <= R) {
                    const int idx = lty * RS + ltx;
                    unsafeAtomicAdd(&tile[0 * PLANE + idx], s0[i]);
                    unsafeAtomicAdd(&tile[1 * PLANE + idx], s1[i]);
                    unsafeAtomicAdd(&tile[2 * PLANE + idx], s2[i]);
                }
            }
        } else {                               // bilinear, 4 corners
#pragma unroll
            for (int i = 0; i < 4; ++i) {
                const int gxi = gx + i;
                const float px = (float)gxi + fx[i];
                const float py = (float)gy  + fy[i];
                const float xf = floorf(px), yf = floorf(py);
                const int x0 = (int)xf, y0 = (int)yf;
                const float wx1 = px - xf, wy1 = py - yf;
                const float wx0 = 1.0f - wx1, wy0 = 1.0f - wy1;

                const int lx0 = x0 - tx0, ly0 = y0 - ty0;
                const int dx0 = x0 - gxi, dy0 = y0 - gy;
                const bool vx0 = ((unsigned)lx0 < (unsigned)TW) &&
                                 (dx0 >= -R) && (dx0 <= R);
                const bool vx1 = ((unsigned)(lx0 + 1) < (unsigned)TW) &&
                                 (dx0 + 1 >= -R) && (dx0 + 1 <= R);
                const bool vy0 = ((unsigned)ly0 < (unsigned)TH) &&
                                 (dy0 >= -R) && (dy0 <= R);
                const bool vy1 = ((unsigned)(ly0 + 1) < (unsigned)TH) &&
                                 (dy0 + 1 >= -R) && (dy0 + 1 <= R);
                if (!((vx0 || vx1) && (vy0 || vy1))) continue;

                const int idx00 = ly0 * RS + lx0;
                if (vy0) {
                    if (vx0) {
                        const float w = wx0 * wy0;
                        unsafeAtomicAdd(&tile[0 * PLANE + idx00], s0[i] * w);
                        unsafeAtomicAdd(&tile[1 * PLANE + idx00], s1[i] * w);
                        unsafeAtomicAdd(&tile[2 * PLANE + idx00], s2[i] * w);
                    }
                    if (vx1) {
                        const float w = wx1 * wy0;
                        unsafeAtomicAdd(&tile[0 * PLANE + idx00 + 1], s0[i] * w);
                        unsafeAtomicAdd(&tile[1 * PLANE + idx00 + 1], s1[i] * w);
                        unsafeAtomicAdd(&tile[2 * PLANE + idx00 + 1], s2[i] * w);
                    }
                }
                if (vy1) {
                    if (vx0) {
                        const float w = wx0 * wy1;
                        unsafeAtomicAdd(&tile[0 * PLANE + idx00 + RS], s0[i] * w);
                        unsafeAtomicAdd(&tile[1 * PLANE + idx00 + RS], s1[i] * w);
                        unsafeAtomicAdd(&tile[2 * PLANE + idx00 + RS], s2[i] * w);
                    }
                    if (vx1) {
                        const float w = wx1 * wy1;
                        unsafeAtomicAdd(&tile[0 * PLANE + idx00 + RS + 1], s0[i] * w);
                        unsafeAtomicAdd(&tile[1 * PLANE + idx00 + RS + 1], s1[i] * w);
                        unsafeAtomicAdd(&tile[2 * PLANE + idx00 + RS + 1], s2[i] * w);
                    }
                }
            }
        }
    }
    __syncthreads();

    // Dense, coalesced, NON-atomic float4 stores (rows 16B-aligned at
    // stride 68): each output pixel is produced by exactly one block.
    for (int i = threadIdx.x; i < C_ * (TW * TH / 4); i += NTHR) {
        const int c    = i >> 10;              // TW*TH/4 == 1024
        const int j    = i & 1023;
        const int row  = j >> 4;               // 16 float4 per 64-wide row
        const int col4 = j & 15;
        const float4 v = *reinterpret_cast<const float4*>(
            &tile[c * PLANE + row * RS + col4 * 4]);
        float* dst = out + ((size_t)(b * C_ + c)) * HW_ +
                     (size_t)(ty0 + row) * W_ + tx0 + col4 * 4;
        *reinterpret_cast<float4*>(dst) = v;
    }
}

// Far pass (stream-ordered after fw_gather): exact complement of the gather
// condition. Flat 1-pixel-per-thread; ~99.5% of threads load->test->exit.
__global__ __launch_bounds__(256) void fw_far(
    const float* __restrict__ im0,
    const float2* __restrict__ flow,
    const int* __restrict__ mode_p,
    float* __restrict__ out) {
    const int idx = blockIdx.x * 256 + threadIdx.x;
    if (idx >= B_ * HW_) return;

    const float2 f = flow[idx];
    // |f.x|<R-1 and |f.y|<R-1 -> all corner disps within [-R, R]:
    // guaranteed handled by gather.
    const float lim = (float)(R - 1);
    if (fabsf(f.x) < lim && fabsf(f.y) < lim) return;

    const int mode = *mode_p;
    const int b   = idx / HW_;
    const int rem = idx - b * HW_;
    const int gy  = rem / W_;
    const int gx  = rem - gy * W_;
    const float px = (float)gx + f.x;
    const float py = (float)gy + f.y;
    const float* im0b = im0 + (size_t)b * C_ * HW_;
    float*       outb = out + (size_t)b * C_ * HW_;
    const int src = gy * W_ + gx;

    if (mode == 1) {
        const int cx = (int)rintf(px);
        const int cy = (int)rintf(py);
        const int dx = cx - gx, dy = cy - gy;
        const bool in = (unsigned)cx < (unsigned)W_ &&
                        (unsigned)cy < (unsigned)H_;
        if (in && (dx < -R || dx > R || dy < -R || dy > R)) {
            const int dsti = cy * W_ + cx;
            unsafeAtomicAdd(outb + dsti,            im0b[src]);
            unsafeAtomicAdd(outb + HW_ + dsti,      im0b[src + HW_]);
            unsafeAtomicAdd(outb + 2 * HW_ + dsti,  im0b[src + 2 * HW_]);
        }
    } else {
        const float xf = floorf(px), yf = floorf(py);
        const int x0 = (int)xf, y0 = (int)yf;
        const float wx1 = px - xf, wy1 = py - yf;
        const float wx0 = 1.0f - wx1, wy0 = 1.0f - wy1;

        const int   cxs[4] = { x0, x0 + 1, x0,     x0 + 1 };
        const int   cys[4] = { y0, y0,     y0 + 1, y0 + 1 };
        const float cws[4] = { wx0 * wy0, wx1 * wy0, wx0 * wy1, wx1 * wy1 };

        bool m[4];
        bool any = false;
#pragma unroll
        for (int k = 0; k < 4; ++k) {
            const int dx = cxs[k] - gx, dy = cys[k] - gy;
            const bool in = (unsigned)cxs[k] < (unsigned)W_ &&
                            (unsigned)cys[k] < (unsigned)H_;
            m[k] = in && (dx < -R || dx > R || dy < -R || dy > R);
            any = any || m[k];
        }
        if (!any) return;

        const float s0 = im0b[src];
        const float s1 = im0b[src + HW_];
        const float s2 = im0b[src + 2 * HW_];
#pragma unroll
        for (int k = 0; k < 4; ++k) {
            if (m[k]) {
                const int dsti = cys[k] * W_ + cxs[k];
                const float w = cws[k];
                unsafeAtomicAdd(outb + dsti,           s0 * w);
                unsafeAtomicAdd(outb + HW_ + dsti,     s1 * w);
                unsafeAtomicAdd(outb + 2 * HW_ + dsti, s2 * w);
            }
        }
    }
}

extern "C" void kernel_launch(void* const* d_in, const int* in_sizes, int n_in,
                              void* d_out, int out_size, void* d_ws, size_t ws_size,
                              hipStream_t stream) {
    const float*  im0  = (const float*)d_in[0];
    const float2* flow = (const float2*)d_in[1];
    // d_in[2] = flowback (unused by the forward splat)
    const int*    mode = (const int*)d_in[3];
    float* out = (float*)d_out;

    // No memset: fw_gather writes every output pixel exactly once with a
    // plain store; fw_far's atomics are stream-ordered after it.
    dim3 grid(W_ / TW, H_ / TH, B_);
    fw_gather<<<grid, dim3(NTHR), 0, stream>>>(im0, flow, mode, out);

    constexpr int total = B_ * HW_;
    fw_far<<<dim3((total + 255) / 256), dim3(256), 0, stream>>>(im0, flow, mode, out);
}